// Round 8
// baseline (194.680 us; speedup 1.0000x reference)
//
#include <hip/hip_runtime.h>
#include <stdint.h>

// Problem constants
#define BATCH 16
#define MGT 256
#define NPROP 8192
#define NUM_CLASSES 80
#define IGNORED_CLASS 80
#define NUM_FG 128
#define NUM_BG 384
#define SENT 0xFFFFFFFFu
#define BS 256
#define CHUNKS_PER_ROW (NPROP / BS)      // 32
#define NUM_BLOCKS (BATCH * CHUNKS_PER_ROW)  // 512

typedef unsigned long long u64;

// d_out FLOAT32 layout (confirmed): matched_vals[16,8192] | matched_idxs[16,8192]
//   | sampled_idxs[16,512] | sampled_classes[16,512] | sampled_gt[16,512]
// ws layout (proven budget: R5 used 1 MiB): packed[B*N] int32 (512 KiB) |
//   done[16] int32 (64 B).  packed = (midx<<16) | (cls+1).

struct SampleSmem {
    uint32_t h32[NPROP];     // 32 KB ordered keys
    uint32_t hist[4096];     // 16 KB
    uint32_t wsums[4];
    uint32_t sc[8];          // b1,p1,b2,p2,b3,p3,C,selcount
    u64      sel[NUM_BG];    // 3 KB
};
union Smem {
    SampleSmem s;
    struct { float sga[MGT]; } m;
};

// ---------------- scan helpers (256 threads = 4 waves) ----------------
__device__ __forceinline__ uint32_t wave_incl_scan_u32(uint32_t x) {
#pragma unroll
    for (int d = 1; d < 64; d <<= 1) {
        uint32_t y = __shfl_up(x, d, 64);
        if ((threadIdx.x & 63) >= d) x += y;
    }
    return x;
}

__device__ uint32_t block_excl_scan(uint32_t s, uint32_t* wsums) {
    const int tid = threadIdx.x, lane = tid & 63, wid = tid >> 6;
    __syncthreads();                 // protect wsums reuse across calls
    uint32_t incl = wave_incl_scan_u32(s);
    if (lane == 63) wsums[wid] = incl;
    __syncthreads();
    if (wid == 0) {
        uint32_t w  = (lane < 4) ? wsums[lane] : 0u;
        uint32_t wi = wave_incl_scan_u32(w);
        if (lane < 4) wsums[lane] = wi - w;
    }
    __syncthreads();
    return wsums[wid] + (incl - s);
}

// inclusive-scan hist[4096]; find bin with incl >= kk > prev; 16 bins/thread.
__device__ void scan_and_find(uint32_t* hist, uint32_t* wsums, uint32_t kk,
                              uint32_t* sc_b, uint32_t* sc_p) {
    const int tid = threadIdx.x;
    __syncthreads();                 // histogram atomics complete
    const int base = tid * 16;
    uint32_t v[16]; uint32_t tot = 0;
#pragma unroll
    for (int j = 0; j < 16; ++j) { v[j] = hist[base + j]; tot += v[j]; }
    uint32_t prev = block_excl_scan(tot, wsums);
#pragma unroll
    for (int j = 0; j < 16; ++j) {
        uint32_t inc = prev + v[j];
        if (inc >= kk && prev < kk) { *sc_b = (uint32_t)(base + j); *sc_p = prev; }
        prev = inc;
    }
    __syncthreads();
}

// ---------------- sample: radix-select top-k for one (row, pass) ------------
__device__ void sample_pass(SampleSmem* S, int b, int pass,
                            const float* __restrict__ pri_f,
                            const int* __restrict__ packed,
                            float* __restrict__ out)
{
    const int tid = threadIdx.x;
    const int K   = pass ? NUM_BG : NUM_FG;
    const int off = pass ? NUM_FG : 0;

    const float* pri = pri_f  + (size_t)b * NPROP;
    const int*   pk  = packed + (size_t)b * NPROP;

    float* s_idx = out + (size_t)2 * BATCH * NPROP + (size_t)b * 512;
    float* s_cls = s_idx + (size_t)BATCH * 512;
    float* s_gt  = s_idx + (size_t)2 * BATCH * 512;

    if (tid < 8) S->sc[tid] = 0u;
    for (int i = tid; i < 4096; i += BS) S->hist[i] = 0u;
    __syncthreads();

    // keys: ~ord(pri) (smaller = higher priority), SENT for masked-out
    uint32_t creal = 0;
#pragma unroll
    for (int it = 0; it < NPROP / BS; ++it) {
        const int i = tid + it * BS;
        const int c = (pk[i] & 0xFFFF) - 1;
        const bool m = pass ? (c == NUM_CLASSES) : (c >= 0 && c != NUM_CLASSES);
        uint32_t v = SENT;
        if (m) {
            uint32_t bits = __float_as_uint(pri[i]);
            uint32_t ord  = (bits & 0x80000000u) ? ~bits : (bits | 0x80000000u);
            v = ~ord;
        }
        S->h32[i] = v;
        u64 bal = __ballot(m);
        if ((tid & 63) == 0) creal += __popcll(bal);
    }
    if ((tid & 63) == 0 && creal) atomicAdd(&S->sc[6], creal);
    __syncthreads();
    const uint32_t C    = S->sc[6];
    const uint32_t ksel = (C < (uint32_t)K) ? C : (uint32_t)K;

    if (C > 0) {
        // L1: bits [31:20]
        for (int i = tid; i < NPROP; i += BS) {
            uint32_t v = S->h32[i];
            if (v < 0x80000000u) atomicAdd(&S->hist[v >> 20], 1u);
        }
        scan_and_find(S->hist, S->wsums, ksel, &S->sc[0], &S->sc[1]);
        const uint32_t b1 = S->sc[0], p1 = S->sc[1];
        const uint32_t k2 = ksel - p1;
        for (int i = tid; i < 4096; i += BS) S->hist[i] = 0u;
        __syncthreads();

        // L2: bits [19:8] within b1
        for (int i = tid; i < NPROP; i += BS) {
            uint32_t v = S->h32[i];
            if ((v >> 20) == b1) atomicAdd(&S->hist[(v >> 8) & 0xFFFu], 1u);
        }
        scan_and_find(S->hist, S->wsums, k2, &S->sc[2], &S->sc[3]);
        const uint32_t b2 = S->sc[2], p2 = S->sc[3];
        const uint32_t k3 = k2 - p2;
        for (int i = tid; i < 4096; i += BS) S->hist[i] = 0u;
        __syncthreads();

        // L3: bits [7:0] within (b1,b2) -> exact k-th key H*
        const uint32_t top24 = (b1 << 12) | b2;
        for (int i = tid; i < NPROP; i += BS) {
            uint32_t v = S->h32[i];
            if ((v >> 8) == top24) atomicAdd(&S->hist[v & 0xFFu], 1u);
        }
        scan_and_find(S->hist, S->wsums, k3, &S->sc[4], &S->sc[5]);
        const uint32_t b3 = S->sc[4], p3 = S->sc[5];
        const uint32_t k4 = k3 - p3;            // ties at H*, taken idx-ascending
        const uint32_t Hstar = (b1 << 20) | (b2 << 8) | b3;

        // tie prefix (idx-ordered contiguous ownership) + compaction
        uint32_t hv[32]; uint32_t ssum = 0;
        const int cbase = tid * 32;
#pragma unroll
        for (int j = 0; j < 32; ++j) { hv[j] = S->h32[cbase + j]; ssum += (hv[j] == Hstar); }
        uint32_t run = block_excl_scan(ssum, S->wsums);
#pragma unroll
        for (int j = 0; j < 32; ++j) {
            bool take = false;
            if (hv[j] < Hstar) take = true;
            else if (hv[j] == Hstar) { take = (run < k4); ++run; }
            if (take) {
                uint32_t pos = atomicAdd(&S->sc[7], 1u);
                S->sel[pos] = ((u64)hv[j] << 32) | (uint32_t)(cbase + j);
            }
        }
        __syncthreads();
        const uint32_t Scnt = S->sc[7];          // == ksel

        // rank scatter: rank = #(keys < mine); keys unique (idx in low bits)
        for (uint32_t j = tid; j < Scnt; j += BS) {
            const u64 kj = S->sel[j];
            uint32_t r = 0;
            for (uint32_t i = 0; i < Scnt; ++i) r += (S->sel[i] < kj);
            const uint32_t idx = (uint32_t)kj;
            const int pv = pk[idx];
            s_idx[off + r] = (float)idx;
            s_cls[off + r] = (float)((pv & 0xFFFF) - 1);
            s_gt[off + r]  = (float)(pv >> 16);
        }
    }

    // filler: first (K - ksel) masked-out indices ascending (invalid slots)
    if (ksel < (uint32_t)K) {
        const uint32_t F = (uint32_t)K - ksel;
        uint32_t hv2[32]; uint32_t sv = 0;
        const int cbase = tid * 32;
#pragma unroll
        for (int j = 0; j < 32; ++j) { hv2[j] = S->h32[cbase + j]; sv += (hv2[j] == SENT); }
        uint32_t run = block_excl_scan(sv, S->wsums);
#pragma unroll
        for (int j = 0; j < 32; ++j) {
            if (hv2[j] == SENT) {
                if (run < F) {
                    const int slot = off + (int)ksel + (int)run;
                    s_idx[slot] = (float)(cbase + j);
                    s_cls[slot] = -1.0f;
                    s_gt[slot]  = -1.0f;
                }
                ++run;
            }
        }
    }
    __syncthreads();   // h32 rewritten by next pass
}

__global__ __launch_bounds__(64) void init_kernel(int* __restrict__ done) {
    if (threadIdx.x < BATCH) done[threadIdx.x] = 0;
}

// 512 blocks. Each matches one chunk; the 32nd finisher of a row samples it.
// No unbounded loops anywhere -> cannot hang.
__global__ __launch_bounds__(BS) void fused_kernel(
    const float* __restrict__ gt_boxes, const int* __restrict__ gt_classes,
    const float* __restrict__ prop_boxes, const float* __restrict__ pri,
    float* __restrict__ out, int* __restrict__ packed, int* __restrict__ done)
{
#pragma clang fp contract(off)
    __shared__ Smem sm;
    __shared__ int s_old;

    const int tid = threadIdx.x;
    const int t   = blockIdx.x;
    const int b   = t >> 5;
    const int n   = ((t & 31) << 8) | tid;

    // ---- match phase ----
    const float4* gt4 = (const float4*)gt_boxes + (size_t)b * MGT;
    {
        float4 g = gt4[tid];
        sm.m.sga[tid] = (g.z - g.x) * (g.w - g.y);   // np op order, no FMA
    }
    __syncthreads();

    const float4 p = ((const float4*)prop_boxes)[(size_t)b * NPROP + n];
    const float ap = (p.z - p.x) * (p.w - p.y);

    float best = 0.0f;   // all IoUs >= 0; argmax(all zeros) = 0
    int   bidx = 0;
    for (int m = 0; m < MGT; ++m) {
        const float4 g = gt4[m];                     // wave-uniform -> s_load
        float ltx = fmaxf(g.x, p.x);
        float lty = fmaxf(g.y, p.y);
        float rbx = fminf(g.z, p.z);
        float rby = fminf(g.w, p.w);
        float w = fmaxf(rbx - ltx, 0.0f);
        float h = fmaxf(rby - lty, 0.0f);
        float inter = w * h;
        float s   = sm.m.sga[m] + ap;                // area_g + area_p
        float uni = s - inter;
        // conservative filter: iou > best requires inter > best*uni (real);
        // thr < best*uni exactly, so no true candidate skipped; division decides.
        float thr = (best * uni) * 0.9999996f;
        if (inter > thr) {
            float iou = (uni > 0.0f) ? (inter / uni) : 0.0f;
            if (iou > best) { best = iou; bidx = m; }   // strict > = first idx
        }
    }

    const bool matched = (best >= 0.5f);
    int c = gt_classes[b * MGT + bidx];
    if (c == IGNORED_CLASS) c = -1;
    if (!matched) c = NUM_CLASSES;

    const size_t on = (size_t)b * NPROP + n;
    out[on]                         = best;
    out[(size_t)BATCH * NPROP + on] = (float)bidx;
    packed[on] = (bidx << 16) | (c + 1);

    // ---- row-completion handshake (device-scope, no waiting) ----
    __syncthreads();                      // all stores issued & drained (vmcnt)
    if (tid == 0) {
        __threadfence();                  // release: publish packed[] row chunk
        s_old = atomicAdd(&done[b], 1);   // device-scope by default
    }
    __syncthreads();
    if (s_old != CHUNKS_PER_ROW - 1) return;   // not the last finisher

    // ---- sample phase (last finisher only; sees all 32 chunks) ----
    __threadfence();                      // acquire: invalidate stale caches
    sample_pass(&sm.s, b, 0, pri, packed, out);
    sample_pass(&sm.s, b, 1, pri, packed, out);
}

extern "C" void kernel_launch(void* const* d_in, const int* in_sizes, int n_in,
                              void* d_out, int out_size, void* d_ws, size_t ws_size,
                              hipStream_t stream) {
    const float* gt_boxes   = (const float*)d_in[0];
    const int*   gt_classes = (const int*)d_in[1];
    const float* prop_boxes = (const float*)d_in[2];
    const float* rand_pri   = (const float*)d_in[3];
    float* out = (float*)d_out;

    int* packed = (int*)d_ws;                         // [B*N] = 512 KiB
    int* done   = packed + (size_t)BATCH * NPROP;     // 16 ints @ 512 KiB offset

    init_kernel<<<1, 64, 0, stream>>>(done);
    fused_kernel<<<NUM_BLOCKS, BS, 0, stream>>>(
        gt_boxes, gt_classes, prop_boxes, rand_pri, out, packed, done);
}

// Round 9
// 145.605 us; speedup vs baseline: 1.3370x; 1.3370x over previous
//
#include <hip/hip_runtime.h>
#include <stdint.h>

// Problem constants
#define BATCH 16
#define MGT 256
#define NPROP 8192
#define NUM_CLASSES 80
#define IGNORED_CLASS 80
#define NUM_FG 128
#define NUM_BG 384
#define SENT 0xFFFFFFFFu
#define BS 1024
#define PPB 512                               // proposals per block (split-M x2)
#define CHUNKS_PER_ROW (NPROP / PPB)          // 16
#define NUM_BLOCKS (BATCH * CHUNKS_PER_ROW)   // 256
#define KPT 8                                 // sample keys per thread

typedef unsigned long long u64;

// d_out FLOAT32 layout (confirmed): matched_vals[16,8192] | matched_idxs[16,8192]
//   | sampled_idxs[16,512] | sampled_classes[16,512] | sampled_gt[16,512]
// ws: packed[B*N] int32 (512 KiB) | done[16] (64 B)  -- R8-proven placement.
// packed = (midx<<16) | (cls+1).

struct SampleSmem {
    uint32_t hist[4096];     // 16 KB
    uint32_t wsums[16];
    uint32_t sc[8];          // b1,p1,b2,p2,b3,p3,C,selcount
    u64      sel[NUM_BG];    // 3 KB
};
struct MatchSmem {
    float sga[MGT];          // 1 KB
    u64   skey[PPB];         // 4 KB
};
union Smem { SampleSmem s; MatchSmem m; };

// ---------------- scan helpers (1024 threads = 16 waves; R5-verified) -------
__device__ __forceinline__ uint32_t wave_incl_scan_u32(uint32_t x) {
#pragma unroll
    for (int d = 1; d < 64; d <<= 1) {
        uint32_t y = __shfl_up(x, d, 64);
        if ((threadIdx.x & 63) >= d) x += y;
    }
    return x;
}

__device__ uint32_t block_excl_scan(uint32_t s, uint32_t* wsums) {
    const int tid = threadIdx.x, lane = tid & 63, wid = tid >> 6;
    __syncthreads();                 // protect wsums reuse across calls
    uint32_t incl = wave_incl_scan_u32(s);
    if (lane == 63) wsums[wid] = incl;
    __syncthreads();
    if (wid == 0) {
        uint32_t w  = (lane < 16) ? wsums[lane] : 0u;
        uint32_t wi = wave_incl_scan_u32(w);
        if (lane < 16) wsums[lane] = wi - w;
    }
    __syncthreads();
    return wsums[wid] + (incl - s);
}

// inclusive-scan hist[4096] in place; find bin with incl >= kk > prev.
__device__ void scan_and_find(uint32_t* hist, uint32_t* wsums, uint32_t kk,
                              uint32_t* sc_b, uint32_t* sc_p) {
    const int tid = threadIdx.x;
    __syncthreads();                 // histogram atomics complete
    const int base = tid * 4;
    uint32_t v0 = hist[base], v1 = hist[base+1], v2 = hist[base+2], v3 = hist[base+3];
    uint32_t pre = block_excl_scan(v0+v1+v2+v3, wsums);
    uint32_t i0 = pre+v0, i1 = i0+v1, i2 = i1+v2, i3 = i2+v3;
    hist[base] = i0; hist[base+1] = i1; hist[base+2] = i2; hist[base+3] = i3;
    __syncthreads();
    uint32_t prev = (base == 0) ? 0u : hist[base-1];
    uint32_t inc[4] = {i0, i1, i2, i3};
#pragma unroll
    for (int j = 0; j < 4; ++j) {
        if (inc[j] >= kk && prev < kk) { *sc_b = (uint32_t)(base+j); *sc_p = prev; }
        prev = inc[j];
    }
    __syncthreads();
}

// ---------------- sample: radix-select top-k, keys in registers -------------
__device__ void sample_pass(SampleSmem* S, int b, int pass,
                            const float* __restrict__ pri_f,
                            const int* __restrict__ packed,
                            float* __restrict__ out)
{
    const int tid = threadIdx.x;
    const int K   = pass ? NUM_BG : NUM_FG;
    const int off = pass ? NUM_FG : 0;

    const float* pri = pri_f  + (size_t)b * NPROP;
    const int*   pk  = packed + (size_t)b * NPROP;

    float* s_idx = out + (size_t)2 * BATCH * NPROP + (size_t)b * 512;
    float* s_cls = s_idx + (size_t)BATCH * 512;
    float* s_gt  = s_idx + (size_t)2 * BATCH * 512;

    if (tid < 8) S->sc[tid] = 0u;
    for (int i = tid; i < 4096; i += BS) S->hist[i] = 0u;
    __syncthreads();

    // keys in registers; cbase = tid*8 -> ascending-index contiguous ownership
    uint32_t key[KPT];
    const int cbase = tid * KPT;
    uint32_t creal = 0;
#pragma unroll
    for (int j = 0; j < KPT; ++j) {
        const int i = cbase + j;
        const int c = (pk[i] & 0xFFFF) - 1;
        const bool m = pass ? (c == NUM_CLASSES) : (c >= 0 && c != NUM_CLASSES);
        uint32_t v = SENT;
        if (m) {
            uint32_t bits = __float_as_uint(pri[i]);
            uint32_t ord  = (bits & 0x80000000u) ? ~bits : (bits | 0x80000000u);
            v = ~ord;                         // smaller == higher priority
        }
        key[j] = v;
        u64 bal = __ballot(m);
        if ((tid & 63) == 0) creal += __popcll(bal);
    }
    if ((tid & 63) == 0 && creal) atomicAdd(&S->sc[6], creal);
    __syncthreads();
    const uint32_t C    = S->sc[6];
    const uint32_t ksel = (C < (uint32_t)K) ? C : (uint32_t)K;

    if (C > 0) {
        // L1: bits [31:20]
#pragma unroll
        for (int j = 0; j < KPT; ++j)
            if (key[j] < 0x80000000u) atomicAdd(&S->hist[key[j] >> 20], 1u);
        scan_and_find(S->hist, S->wsums, ksel, &S->sc[0], &S->sc[1]);
        const uint32_t b1 = S->sc[0], p1 = S->sc[1];
        const uint32_t k2 = ksel - p1;
        for (int i = tid; i < 4096; i += BS) S->hist[i] = 0u;
        __syncthreads();

        // L2: bits [19:8] within b1
#pragma unroll
        for (int j = 0; j < KPT; ++j)
            if ((key[j] >> 20) == b1) atomicAdd(&S->hist[(key[j] >> 8) & 0xFFFu], 1u);
        scan_and_find(S->hist, S->wsums, k2, &S->sc[2], &S->sc[3]);
        const uint32_t b2 = S->sc[2], p2 = S->sc[3];
        const uint32_t k3 = k2 - p2;
        for (int i = tid; i < 4096; i += BS) S->hist[i] = 0u;
        __syncthreads();

        // L3: bits [7:0] within (b1,b2) -> exact k-th key H*
        const uint32_t top24 = (b1 << 12) | b2;
#pragma unroll
        for (int j = 0; j < KPT; ++j)
            if ((key[j] >> 8) == top24) atomicAdd(&S->hist[key[j] & 0xFFu], 1u);
        scan_and_find(S->hist, S->wsums, k3, &S->sc[4], &S->sc[5]);
        const uint32_t b3 = S->sc[4], p3 = S->sc[5];
        const uint32_t k4 = k3 - p3;          // ties at H*, taken idx-ascending
        const uint32_t Hstar = (b1 << 20) | (b2 << 8) | b3;

        // tie prefix (idx-ordered) + compaction into sel[]
        uint32_t ssum = 0;
#pragma unroll
        for (int j = 0; j < KPT; ++j) ssum += (key[j] == Hstar);
        uint32_t run = block_excl_scan(ssum, S->wsums);
#pragma unroll
        for (int j = 0; j < KPT; ++j) {
            bool take = false;
            if (key[j] < Hstar) take = true;
            else if (key[j] == Hstar) { take = (run < k4); ++run; }
            if (take) {
                uint32_t pos = atomicAdd(&S->sc[7], 1u);
                S->sel[pos] = ((u64)key[j] << 32) | (uint32_t)(cbase + j);
            }
        }
        __syncthreads();
        const uint32_t Scnt = S->sc[7];       // == ksel

        // rank scatter: rank = #(keys < mine); keys unique (idx in low bits)
        for (uint32_t j = tid; j < Scnt; j += BS) {
            const u64 kj = S->sel[j];
            uint32_t r = 0;
            for (uint32_t i = 0; i < Scnt; ++i) r += (S->sel[i] < kj);
            const uint32_t idx = (uint32_t)kj;
            const int pv = pk[idx];
            s_idx[off + r] = (float)idx;
            s_cls[off + r] = (float)((pv & 0xFFFF) - 1);
            s_gt[off + r]  = (float)(pv >> 16);
        }
    }

    // filler: first (K - ksel) masked-out indices ascending (invalid slots)
    if (ksel < (uint32_t)K) {
        const uint32_t F = (uint32_t)K - ksel;
        uint32_t sv = 0;
#pragma unroll
        for (int j = 0; j < KPT; ++j) sv += (key[j] == SENT);
        uint32_t run = block_excl_scan(sv, S->wsums);
#pragma unroll
        for (int j = 0; j < KPT; ++j) {
            if (key[j] == SENT) {
                if (run < F) {
                    const int slot = off + (int)ksel + (int)run;
                    s_idx[slot] = (float)(cbase + j);
                    s_cls[slot] = -1.0f;
                    s_gt[slot]  = -1.0f;
                }
                ++run;
            }
        }
    }
    __syncthreads();   // isolate passes
}

__global__ __launch_bounds__(64) void init_kernel(int* __restrict__ done) {
    if (threadIdx.x < BATCH) done[threadIdx.x] = 0;
}

// 256 blocks x 1024 threads. Each matches 512 proposals (split-M x2);
// the 16th finisher of a row runs both sample passes at full width.
__global__ __launch_bounds__(BS) void fused_kernel(
    const float* __restrict__ gt_boxes, const int* __restrict__ gt_classes,
    const float* __restrict__ prop_boxes, const float* __restrict__ pri,
    float* __restrict__ out, int* __restrict__ packed, int* __restrict__ done)
{
#pragma clang fp contract(off)
    __shared__ Smem sm;
    __shared__ int s_old;

    const int tid = threadIdx.x;
    const int b   = blockIdx.x >> 4;            // 16 chunks/row
    const int n   = ((blockIdx.x & 15) << 9) | (tid & (PPB - 1));
    const int half = tid >> 9;                  // uniform per wave (waves 0-7 / 8-15)

    // ---- match phase ----
    const float4* gt4 = (const float4*)gt_boxes + (size_t)b * MGT;
    if (tid < MGT) {
        float4 g = gt4[tid];
        sm.m.sga[tid] = (g.z - g.x) * (g.w - g.y);   // np op order, no FMA
    }
    __syncthreads();

    const float4 p = ((const float4*)prop_boxes)[(size_t)b * NPROP + n];
    const float ap = (p.z - p.x) * (p.w - p.y);

    float best = 0.0f;
    int   bidx = 0;
    const int m0 = half * 128;
    for (int mm = 0; mm < 128; ++mm) {
        const int m = m0 + mm;
        const float4 g = gt4[m];                     // wave-uniform -> s_load
        float ltx = fmaxf(g.x, p.x);
        float lty = fmaxf(g.y, p.y);
        float rbx = fminf(g.z, p.z);
        float rby = fminf(g.w, p.w);
        float w = fmaxf(rbx - ltx, 0.0f);
        float h = fmaxf(rby - lty, 0.0f);
        float inter = w * h;
        float s   = sm.m.sga[m] + ap;                // area_g + area_p
        float uni = s - inter;
        // conservative filter (R8-verified): no true candidate skipped
        float thr = (best * uni) * 0.9999996f;
        if (inter > thr) {
            float iou = (uni > 0.0f) ? (inter / uni) : 0.0f;
            if (iou > best) { best = iou; bidx = m; }   // strict > = first idx
        }
    }
    // combine halves: max key = larger iou, tie -> smaller gt idx (R5-verified)
    u64 key = ((u64)__float_as_uint(best) << 32) | (uint32_t)(255 - bidx);
    const int pl = tid & (PPB - 1);
    if (half) sm.m.skey[pl] = key;
    __syncthreads();
    if (half == 0) {
        u64 o = sm.m.skey[pl];
        if (o > key) key = o;
        float bestf = __uint_as_float((uint32_t)(key >> 32));
        int   bi    = 255 - (int)(key & 0xFFu);

        const bool matched = (bestf >= 0.5f);
        int c = gt_classes[b * MGT + bi];
        if (c == IGNORED_CLASS) c = -1;
        if (!matched) c = NUM_CLASSES;

        const size_t on = (size_t)b * NPROP + n;
        out[on]                         = bestf;
        out[(size_t)BATCH * NPROP + on] = (float)bi;
        packed[on] = (bi << 16) | (c + 1);
    }

    // ---- row-completion handshake (R8-proven) ----
    __syncthreads();
    if (tid == 0) {
        __threadfence();                  // release: publish packed[] chunk
        s_old = atomicAdd(&done[b], 1);
    }
    __syncthreads();
    if (s_old != CHUNKS_PER_ROW - 1) return;

    // ---- sample phase (last finisher; full 1024-thread width) ----
    __threadfence();                      // acquire
    sample_pass(&sm.s, b, 0, pri, packed, out);
    sample_pass(&sm.s, b, 1, pri, packed, out);
}

extern "C" void kernel_launch(void* const* d_in, const int* in_sizes, int n_in,
                              void* d_out, int out_size, void* d_ws, size_t ws_size,
                              hipStream_t stream) {
    const float* gt_boxes   = (const float*)d_in[0];
    const int*   gt_classes = (const int*)d_in[1];
    const float* prop_boxes = (const float*)d_in[2];
    const float* rand_pri   = (const float*)d_in[3];
    float* out = (float*)d_out;

    int* packed = (int*)d_ws;                         // [B*N] = 512 KiB
    int* done   = packed + (size_t)BATCH * NPROP;     // 16 ints @ 512 KiB

    init_kernel<<<1, 64, 0, stream>>>(done);
    fused_kernel<<<NUM_BLOCKS, BS, 0, stream>>>(
        gt_boxes, gt_classes, prop_boxes, rand_pri, out, packed, done);
}